// Round 19
// baseline (237.781 us; speedup 1.0000x reference)
//
#include <hip/hip_runtime.h>
#include <hip/hip_fp16.h>

// CSPN: 24 diffusion steps fused T=6/launch, 4 launches, NO materialized K.
// K recomputed in-kernel from ORIGINAL x (L2-resident) and held in the
// round-11-proven PACKED fp16 layout (16 half2 + float4 k0 ~= 20 VGPR
// persistent) - r17/r18's fp32 K (36 regs) was spilled by the RA
// (VGPR_Count=40, +17us scratch). Conv math fp32 -> packed once.
constexpr int B = 8, H = 512, W = 512;
constexpr int N = B * H * W;       // 2,097,152
constexpr int HW = H * W;

constexpr int TT = 32;             // output tile side
constexpr int T  = 6;              // fused steps per launch (24 = 4*6)
constexpr int XR = TT + 2 * T;     // 44: staged X region side
constexpr int XE = XR * XR;        // 1936 floats per buffer
constexpr int NG = XR / 4;         // 11 col-groups per row
constexpr int CR = XR - 2;         // 42 computed rows (xi = 1..42)
constexpr int NGT = CR * NG;       // 462 active threads
constexpr int NTH = H / TT, NTW = W / TT;   // 16 x 16
constexpr int NTILES = B * NTH * NTW;       // 2048 (div by 8 -> bijective swz)
constexpr int NT = 512;
constexpr int NF2 = XR * (XR / 2); // 968 float2 to stage

#define H2F(h) __half2float(h)

__global__ __launch_bounds__(NT, 6) void cspn_fused(
    const float* __restrict__ x0, const float* __restrict__ Wa,
    const float* __restrict__ ba, const float* __restrict__ xin,
    float* __restrict__ xout) {
  __shared__ __align__(16) float sBuf[64 + 2 * XE + 64];  // front/back guards
  float* sX = sBuf + 64;

  int bid = blockIdx.x;
  int wg = (bid & 7) * (NTILES / 8) + (bid >> 3);  // XCD-chunked swizzle
  int b  = wg / (NTH * NTW);
  int rr = wg % (NTH * NTW);
  int ti0 = (rr / NTW) * TT, tj0 = (rr % NTW) * TT;
  int tid = threadIdx.x;

  bool active = tid < NGT;
  int xi  = 1 + tid / NG;          // 1..42
  int xj0 = (tid % NG) * 4;        // 0,4,...,40

  const float* xb  = xin + (size_t)b * HW;
  const float* x0b = x0 + (size_t)b * HW;

  // ---- issue staging loads FIRST ----
  int li0 = tid / (XR / 2), gc0 = tid - li0 * (XR / 2);
  int p1 = tid + NT;
  int li1 = p1 / (XR / 2), gc1 = p1 - li1 * (XR / 2);
  bool st1 = p1 < NF2;
  float2 sv0 = make_float2(0.f, 0.f), sv1 = make_float2(0.f, 0.f);
  {
    int gi = ti0 + li0 - T, gj = tj0 + 2 * gc0 - T;
    if ((unsigned)gi < (unsigned)H && (unsigned)gj < (unsigned)W)
      sv0 = *reinterpret_cast<const float2*>(xb + gi * W + gj);
  }
  if (st1) {
    int gi = ti0 + li1 - T, gj = tj0 + 2 * gc1 - T;
    if ((unsigned)gi < (unsigned)H && (unsigned)gj < (unsigned)W)
      sv1 = *reinterpret_cast<const float2*>(xb + gi * W + gj);
  }

  // ---- K window loads (branchless clamp + select; L2-hit) ----
  int gi  = ti0 + xi - T;          // K row
  int gj0 = tj0 + xj0 - T;         // K col base
  bool rowv = (unsigned)gi < (unsigned)H;
  float rv[3][6];
#pragma unroll
  for (int r = 0; r < 3; ++r) {
    int ii = gi - 1 + r;
    bool rok = (unsigned)ii < (unsigned)H;
    int iic = min(max(ii, 0), H - 1);
    const float* row = x0b + (size_t)iic * W;
#pragma unroll
    for (int q = 0; q < 6; ++q) {
      int jj = gj0 - 1 + q;
      int jjc = min(max(jj, 0), W - 1);
      float v = row[jjc];
      rv[r][q] = (rok && (unsigned)jj < (unsigned)W) ? v : 0.f;
    }
  }

  // ---- write staged values + zero guards/borders (shrinks reg peak) ----
  *reinterpret_cast<float2*>(sX + li0 * XR + 2 * gc0) = sv0;
  if (st1) *reinterpret_cast<float2*>(sX + li1 * XR + 2 * gc1) = sv1;
  if (tid < 64) {
    sBuf[tid] = 0.f;
    sBuf[64 + 2 * XE + tid] = 0.f;
  }
  if (tid < 2 * XR) {              // buf1 rows 0 and 43
    int r = (tid < XR) ? 0 : (XR - 1);
    int c = (tid < XR) ? tid : tid - XR;
    sX[XE + r * XR + c] = 0.f;
  }

  // ---- K fragment: fp32 conv+normalize -> PACKED fp16 (r11 layout) ----
  __half2 kh[4][4];                // [px][tap-pair] (a1,a2)(a3,a4)(a5,a6)(a7,a8)
  float4 k0;                       // fp32 center tap per px
  {
    float k0v[4];
#pragma unroll
    for (int p = 0; p < 4; ++p) {
      float aff[8];
      float abs_sum = 0.f;
#pragma unroll
      for (int c = 0; c < 8; ++c) {
        float a = ba[c];
#pragma unroll
        for (int u = 0; u < 3; ++u)
#pragma unroll
          for (int q = 0; q < 3; ++q)
            a += rv[u][p + q] * Wa[c * 9 + u * 3 + q];
        aff[c] = a;
        abs_sum += fabsf(a);
      }
      float inv = 1.0f / abs_sum;
      float s = 0.f;
#pragma unroll
      for (int c = 0; c < 8; ++c) {
        aff[c] *= inv;
        s += aff[c];
      }
      bool pxv = rowv && (unsigned)(gj0 + p) < (unsigned)W;
      k0v[p] = pxv ? (1.0f - s) : 1.0f;   // invalid px: copy self (0)
#pragma unroll
      for (int c = 0; c < 4; ++c)
        kh[p][c] = pxv ? __floats2half2_rn(aff[2 * c], aff[2 * c + 1])
                       : __floats2half2_rn(0.f, 0.f);
    }
    k0 = make_float4(k0v[0], k0v[1], k0v[2], k0v[3]);
  }
  __syncthreads();

  // ---- T fused steps; own 4 px live in c1 ----
  int base = xi * XR + xj0;
  float4 c1;
  if (active) c1 = *reinterpret_cast<const float4*>(sX + base);
#pragma unroll
  for (int s = 0; s < T; ++s) {
    const float* Xc = sX + (s & 1) * XE;
    float* Xn = sX + (((s & 1) ^ 1)) * XE;
    if (active) {
      // edge-pair bases: offsets 0 and 5 -> ds_read2_b32
      const float* eu = Xc + base - XR - 1;
      const float* ed = Xc + base + XR - 1;
      const float* ec = Xc + base - 1;
      float l0 = eu[0], r0 = eu[5];
      float l1 = ec[0], r1 = ec[5];
      float l2 = ed[0], r2 = ed[5];
      float4 c0 = *reinterpret_cast<const float4*>(eu + 1);  // base-XR
      float4 c2 = *reinterpret_cast<const float4*>(ed + 1);  // base+XR
      float4 acc;
      acc.x = k0.x * c1.x
            + H2F(kh[0][0].x) * l1   + H2F(kh[0][0].y) * c1.y
            + H2F(kh[0][1].x) * c0.x + H2F(kh[0][1].y) * l0
            + H2F(kh[0][2].x) * c0.y + H2F(kh[0][2].y) * c2.x
            + H2F(kh[0][3].x) * l2   + H2F(kh[0][3].y) * c2.y;
      acc.y = k0.y * c1.y
            + H2F(kh[1][0].x) * c1.x + H2F(kh[1][0].y) * c1.z
            + H2F(kh[1][1].x) * c0.y + H2F(kh[1][1].y) * c0.x
            + H2F(kh[1][2].x) * c0.z + H2F(kh[1][2].y) * c2.y
            + H2F(kh[1][3].x) * c2.x + H2F(kh[1][3].y) * c2.z;
      acc.z = k0.z * c1.z
            + H2F(kh[2][0].x) * c1.y + H2F(kh[2][0].y) * c1.w
            + H2F(kh[2][1].x) * c0.z + H2F(kh[2][1].y) * c0.y
            + H2F(kh[2][2].x) * c0.w + H2F(kh[2][2].y) * c2.z
            + H2F(kh[2][3].x) * c2.y + H2F(kh[2][3].y) * c2.w;
      acc.w = k0.w * c1.w
            + H2F(kh[3][0].x) * c1.z + H2F(kh[3][0].y) * r1
            + H2F(kh[3][1].x) * c0.w + H2F(kh[3][1].y) * c0.z
            + H2F(kh[3][2].x) * r0   + H2F(kh[3][2].y) * c2.w
            + H2F(kh[3][3].x) * c2.z + H2F(kh[3][3].y) * r2;
      *reinterpret_cast<float4*>(Xn + base) = acc;
      c1 = acc;
    }
    __syncthreads();
  }

  // ---- write 32x32 tile (step-6 result is in buf0; T even) ----
  float* yb = xout + (size_t)b * HW;
  int i  = tid >> 4;               // 0..31
  int pj = (tid & 15) * 2;         // 0..30
  float2 v = *reinterpret_cast<const float2*>(sX + (i + T) * XR + (pj + T));
  *reinterpret_cast<float2*>(yb + (size_t)(ti0 + i) * W + (tj0 + pj)) = v;
}

extern "C" void kernel_launch(void* const* d_in, const int* in_sizes, int n_in,
                              void* d_out, int out_size, void* d_ws,
                              size_t ws_size, hipStream_t stream) {
  const float* x  = (const float*)d_in[0];
  const float* Wa = (const float*)d_in[1];
  const float* ba = (const float*)d_in[2];
  float* out = (float*)d_out;
  float* xa = (float*)d_ws;            // N floats ping-pong buffer

  const float* src = x;
  for (int l = 0; l < 24 / T; ++l) {   // 4 launches of 6 fused steps
    float* dst = (l & 1) ? out : xa;   // l=3 (odd) -> final lands in d_out
    cspn_fused<<<dim3(NTILES), dim3(NT), 0, stream>>>(x, Wa, ba, src, dst);
    src = dst;
  }
}

// Round 20
// 114.805 us; speedup vs baseline: 2.0712x; 2.0712x over previous
//
#include <hip/hip_runtime.h>
#include <hip/hip_fp16.h>

// CSPN: affinity conv -> 8 a-planes fp16 AoS (16 B/px) -> 24 diffusion steps
// fused T=6/launch. ROUND-15 WINNER VERBATIM (115.1 us measured): scalar gen,
// fused = 4-px threads + c1 register carry + ds_read2 edge pairs +
// stage-loads-first + launch_bounds(512,6).
// Post-mortem ledger: K-recompute in fused (r17-19) = net VALU loss + RA
// spill (VGPR pinned 40, scratch traffic); vectorized gen (r13/14) = -10us;
// 8px/thread (r12) and (512,8) (r13) = occupancy losses. Do not revisit.
constexpr int B = 8, H = 512, W = 512;
constexpr int N = B * H * W;       // 2,097,152
constexpr int HW = H * W;

constexpr int TT = 32;             // output tile side
constexpr int T  = 6;              // fused steps per launch (24 = 4*6)
constexpr int XR = TT + 2 * T;     // 44: staged X region side
constexpr int XE = XR * XR;        // 1936 floats per buffer
constexpr int NG = XR / 4;         // 11 col-groups per row
constexpr int CR = XR - 2;         // 42 computed rows (xi = 1..42)
constexpr int NGT = CR * NG;       // 462 active threads
constexpr int NTH = H / TT, NTW = W / TT;   // 16 x 16
constexpr int NTILES = B * NTH * NTW;       // 2048 (div by 8 -> bijective swz)
constexpr int NT = 512;
constexpr int NF2 = XR * (XR / 2); // 968 float2 to stage

// ---------------------------------------------------------------------------
// Kernel 1: affinity conv (1->8, 3x3 SAME) + bias -> normalize -> fp16 AoS.
// Scalar 1 px/thread (measured ~15us; vectorized variant regressed ~10us).
// ---------------------------------------------------------------------------
__global__ __launch_bounds__(256) void cspn_gen_kernel(
    const float* __restrict__ x, const float* __restrict__ Wa,
    const float* __restrict__ ba, __half* __restrict__ Kh) {
  int idx = blockIdx.x * 256 + threadIdx.x;
  if (idx >= N) return;
  int j = idx & (W - 1);
  int i = (idx >> 9) & (H - 1);
  const float* xb = x + (idx & ~(HW - 1));

  float v[9];
#pragma unroll
  for (int u = 0; u < 3; ++u) {
#pragma unroll
    for (int t = 0; t < 3; ++t) {
      int ii = i + u - 1, jj = j + t - 1;
      v[u * 3 + t] = (unsigned(ii) < (unsigned)H && unsigned(jj) < (unsigned)W)
                         ? xb[ii * W + jj]
                         : 0.0f;
    }
  }

  float aff[8];
  float abs_sum = 0.0f;
#pragma unroll
  for (int c = 0; c < 8; ++c) {
    float a = ba[c];
#pragma unroll
    for (int t = 0; t < 9; ++t) a += v[t] * Wa[c * 9 + t];
    aff[c] = a;
    abs_sum += fabsf(a);
  }
  float inv = 1.0f / abs_sum;
#pragma unroll
  for (int c = 0; c < 8; ++c) aff[c] *= inv;

  union { uint4 u; __half2 h[4]; } pk;
#pragma unroll
  for (int c = 0; c < 4; ++c)
    pk.h[c] = __floats2half2_rn(aff[2 * c], aff[2 * c + 1]);
  *reinterpret_cast<uint4*>(Kh + (size_t)idx * 8) = pk.u;
}

// ---------------------------------------------------------------------------
// Kernel 2: T=6 fused steps, 32x32 tile, X region 44x44 double-buffered.
// Thread owns 4-px group (xi, xj0..+3); K packed fp16 (16 half2 + 4 fp32 K0);
// own 4 px ride in c1. Edge scalars read as read2 pairs (base, offs 0/5).
// launch_bounds(512,6): 3 blocks/CU, no spill.
// ---------------------------------------------------------------------------
#define H2F(h) __half2float(h)

__global__ __launch_bounds__(NT, 6) void cspn_fused(
    const float* __restrict__ xin, const __half* __restrict__ Kh,
    float* __restrict__ xout) {
  __shared__ __align__(16) float sBuf[64 + 2 * XE + 64];  // front/back guards
  float* sX = sBuf + 64;

  int bid = blockIdx.x;
  int wg = (bid & 7) * (NTILES / 8) + (bid >> 3);  // XCD-chunked swizzle
  int b  = wg / (NTH * NTW);
  int rr = wg % (NTH * NTW);
  int ti0 = (rr / NTW) * TT, tj0 = (rr % NTW) * TT;
  int tid = threadIdx.x;

  bool active = tid < NGT;
  int xi  = 1 + tid / NG;          // 1..42
  int xj0 = (tid % NG) * 4;        // 0,4,...,40

  const float* xb = xin + (size_t)b * HW;

  // ---- issue staging loads FIRST (latency overlaps K load+unpack) ----
  int li0 = tid / (XR / 2), gc0 = tid - li0 * (XR / 2);
  int p1 = tid + NT;
  int li1 = p1 / (XR / 2), gc1 = p1 - li1 * (XR / 2);
  bool st1 = p1 < NF2;
  float2 sv0 = make_float2(0.f, 0.f), sv1 = make_float2(0.f, 0.f);
  {
    int gi = ti0 + li0 - T, gj = tj0 + 2 * gc0 - T;
    if ((unsigned)gi < (unsigned)H && (unsigned)gj < (unsigned)W)
      sv0 = *reinterpret_cast<const float2*>(xb + gi * W + gj);
  }
  if (st1) {
    int gi = ti0 + li1 - T, gj = tj0 + 2 * gc1 - T;
    if ((unsigned)gi < (unsigned)H && (unsigned)gj < (unsigned)W)
      sv1 = *reinterpret_cast<const float2*>(xb + gi * W + gj);
  }

  // ---- one-time K fragment: 4 px x half8, kept PACKED (16 half2 regs) ----
  __half2 kh[4][4];                // [px][tap-pair]
  float4 k0;                       // fp32 center tap per px
  {
    int gi  = ti0 + xi - T;
    int gj0 = tj0 + xj0 - T;
    bool rowv = active && (unsigned)gi < (unsigned)H;
    const __half* Kb =
        Kh + ((size_t)b * HW + (size_t)(rowv ? gi : 0) * W) * 8;
    float k0v[4];
#pragma unroll
    for (int p = 0; p < 4; ++p) {
      int gj = gj0 + p;
      union { uint4 u; __half2 h[4]; } pk;
      pk.u = make_uint4(0u, 0u, 0u, 0u);
      if (rowv && (unsigned)gj < (unsigned)W)
        pk.u = *reinterpret_cast<const uint4*>(Kb + (size_t)gj * 8);
      float2 f01 = __half22float2(pk.h[0]);
      float2 f23 = __half22float2(pk.h[1]);
      float2 f45 = __half22float2(pk.h[2]);
      float2 f67 = __half22float2(pk.h[3]);
      k0v[p] = 1.0f - (f01.x + f01.y + f23.x + f23.y +
                       f45.x + f45.y + f67.x + f67.y);
      kh[p][0] = pk.h[0]; kh[p][1] = pk.h[1];
      kh[p][2] = pk.h[2]; kh[p][3] = pk.h[3];
    }
    k0 = make_float4(k0v[0], k0v[1], k0v[2], k0v[3]);
  }

  // ---- write staged values to LDS buf0; zero guards + buf1 border rows ----
  *reinterpret_cast<float2*>(sX + li0 * XR + 2 * gc0) = sv0;
  if (st1) *reinterpret_cast<float2*>(sX + li1 * XR + 2 * gc1) = sv1;
  if (tid < 64) {
    sBuf[tid] = 0.f;
    sBuf[64 + 2 * XE + tid] = 0.f;
  }
  if (tid < 2 * XR) {              // buf1 rows 0 and 43
    int r = (tid < XR) ? 0 : (XR - 1);
    int c = (tid < XR) ? tid : tid - XR;
    sX[XE + r * XR + c] = 0.f;
  }
  __syncthreads();

  // ---- T fused steps; own 4 px live in c1 ----
  int base = xi * XR + xj0;
  float4 c1;
  if (active) c1 = *reinterpret_cast<const float4*>(sX + base);
#pragma unroll
  for (int s = 0; s < T; ++s) {
    const float* Xc = sX + (s & 1) * XE;
    float* Xn = sX + (((s & 1) ^ 1)) * XE;
    if (active) {
      // edge-pair bases: offsets 0 and 5 -> ds_read2_b32
      const float* eu = Xc + base - XR - 1;
      const float* ec = Xc + base - 1;
      const float* ed = Xc + base + XR - 1;
      float l0 = eu[0], r0 = eu[5];
      float l1 = ec[0], r1 = ec[5];
      float l2 = ed[0], r2 = ed[5];
      float4 c0 = *reinterpret_cast<const float4*>(eu + 1);  // base-XR, 16B al.
      float4 c2 = *reinterpret_cast<const float4*>(ed + 1);  // base+XR, 16B al.
      float4 acc;
      acc.x = k0.x * c1.x
            + H2F(kh[0][0].x) * l1   + H2F(kh[0][0].y) * c1.y
            + H2F(kh[0][1].x) * c0.x + H2F(kh[0][1].y) * l0
            + H2F(kh[0][2].x) * c0.y + H2F(kh[0][2].y) * c2.x
            + H2F(kh[0][3].x) * l2   + H2F(kh[0][3].y) * c2.y;
      acc.y = k0.y * c1.y
            + H2F(kh[1][0].x) * c1.x + H2F(kh[1][0].y) * c1.z
            + H2F(kh[1][1].x) * c0.y + H2F(kh[1][1].y) * c0.x
            + H2F(kh[1][2].x) * c0.z + H2F(kh[1][2].y) * c2.y
            + H2F(kh[1][3].x) * c2.x + H2F(kh[1][3].y) * c2.z;
      acc.z = k0.z * c1.z
            + H2F(kh[2][0].x) * c1.y + H2F(kh[2][0].y) * c1.w
            + H2F(kh[2][1].x) * c0.z + H2F(kh[2][1].y) * c0.y
            + H2F(kh[2][2].x) * c0.w + H2F(kh[2][2].y) * c2.z
            + H2F(kh[2][3].x) * c2.y + H2F(kh[2][3].y) * c2.w;
      acc.w = k0.w * c1.w
            + H2F(kh[3][0].x) * c1.z + H2F(kh[3][0].y) * r1
            + H2F(kh[3][1].x) * c0.w + H2F(kh[3][1].y) * c0.z
            + H2F(kh[3][2].x) * r0   + H2F(kh[3][2].y) * c2.w
            + H2F(kh[3][3].x) * c2.z + H2F(kh[3][3].y) * r2;
      *reinterpret_cast<float4*>(Xn + base) = acc;
      c1 = acc;
    }
    __syncthreads();
  }

  // ---- write 32x32 tile (step-6 result is in buf0; T even) ----
  float* yb = xout + (size_t)b * HW;
  int i  = tid >> 4;               // 0..31
  int pj = (tid & 15) * 2;         // 0..30
  float2 v = *reinterpret_cast<const float2*>(sX + (i + T) * XR + (pj + T));
  *reinterpret_cast<float2*>(yb + (size_t)(ti0 + i) * W + (tj0 + pj)) = v;
}

extern "C" void kernel_launch(void* const* d_in, const int* in_sizes, int n_in,
                              void* d_out, int out_size, void* d_ws,
                              size_t ws_size, hipStream_t stream) {
  const float* x  = (const float*)d_in[0];
  const float* Wa = (const float*)d_in[1];
  const float* ba = (const float*)d_in[2];
  float* out = (float*)d_out;

  __half* Kh = (__half*)d_ws;                   // 8N halves = 33.5 MB
  float* xa = (float*)d_ws + 4 * (size_t)N;     // after 16N bytes
  cspn_gen_kernel<<<dim3(N / 256), dim3(256), 0, stream>>>(x, Wa, ba, Kh);

  const float* src = x;
  for (int l = 0; l < 24 / T; ++l) {   // 4 launches of 6 fused steps
    float* dst = (l & 1) ? out : xa;   // l=3 (odd) -> final lands in d_out
    cspn_fused<<<dim3(NTILES), dim3(NT), 0, stream>>>(src, Kh, dst);
    src = dst;
  }
}

// Round 21
// 110.609 us; speedup vs baseline: 2.1497x; 1.0379x over previous
//
#include <hip/hip_runtime.h>
#include <hip/hip_fp16.h>

// CSPN: affinity conv -> 8 a-planes fp16 AoS -> 24 diffusion steps fused
// T=6/launch. Round-15 structure + EDGE SCALARS VIA DPP WAVE-SHIFTS:
// the 3 ds_read2 edge reads were a 16-way bank conflict (64 words into 8
// banks, cols ≡3 / ≡0 mod 4; 6.4M conflict cyc/dispatch measured r17/18).
// l*/r* edges = neighbor lane's c0/c1/c2 components -> update_dpp
// wave_shr1/wave_shl1 (VALU, no LDS). Lane 0/63 fall back to 1-lane LDS
// reads. Bit-identical to r15/r20 (absmax must be exactly 524288).
// Ledger: K-recompute (r17-19) = RA spill; vec gen (r13/14) = -10us;
// 8px/thread (r12), (512,8) (r13) = occupancy loss. Do not revisit.
constexpr int B = 8, H = 512, W = 512;
constexpr int N = B * H * W;       // 2,097,152
constexpr int HW = H * W;

constexpr int TT = 32;             // output tile side
constexpr int T  = 6;              // fused steps per launch (24 = 4*6)
constexpr int XR = TT + 2 * T;     // 44: staged X region side
constexpr int XE = XR * XR;        // 1936 floats per buffer
constexpr int NG = XR / 4;         // 11 col-groups per row
constexpr int CR = XR - 2;         // 42 computed rows (xi = 1..42)
constexpr int NGT = CR * NG;       // 462 active threads
constexpr int NTH = H / TT, NTW = W / TT;   // 16 x 16
constexpr int NTILES = B * NTH * NTW;       // 2048 (div by 8 -> bijective swz)
constexpr int NT = 512;
constexpr int NF2 = XR * (XR / 2); // 968 float2 to stage

// ---------------------------------------------------------------------------
// Kernel 1: affinity conv (1->8, 3x3 SAME) + bias -> normalize -> fp16 AoS.
// Scalar 1 px/thread (measured ~15us; vectorized variant regressed ~10us).
// ---------------------------------------------------------------------------
__global__ __launch_bounds__(256) void cspn_gen_kernel(
    const float* __restrict__ x, const float* __restrict__ Wa,
    const float* __restrict__ ba, __half* __restrict__ Kh) {
  int idx = blockIdx.x * 256 + threadIdx.x;
  if (idx >= N) return;
  int j = idx & (W - 1);
  int i = (idx >> 9) & (H - 1);
  const float* xb = x + (idx & ~(HW - 1));

  float v[9];
#pragma unroll
  for (int u = 0; u < 3; ++u) {
#pragma unroll
    for (int t = 0; t < 3; ++t) {
      int ii = i + u - 1, jj = j + t - 1;
      v[u * 3 + t] = (unsigned(ii) < (unsigned)H && unsigned(jj) < (unsigned)W)
                         ? xb[ii * W + jj]
                         : 0.0f;
    }
  }

  float aff[8];
  float abs_sum = 0.0f;
#pragma unroll
  for (int c = 0; c < 8; ++c) {
    float a = ba[c];
#pragma unroll
    for (int t = 0; t < 9; ++t) a += v[t] * Wa[c * 9 + t];
    aff[c] = a;
    abs_sum += fabsf(a);
  }
  float inv = 1.0f / abs_sum;
#pragma unroll
  for (int c = 0; c < 8; ++c) aff[c] *= inv;

  union { uint4 u; __half2 h[4]; } pk;
#pragma unroll
  for (int c = 0; c < 4; ++c)
    pk.h[c] = __floats2half2_rn(aff[2 * c], aff[2 * c + 1]);
  *reinterpret_cast<uint4*>(Kh + (size_t)idx * 8) = pk.u;
}

// ---------------------------------------------------------------------------
// DPP wave shifts: lane n <- lane n-1 (shr) / lane n+1 (shl). No-source
// lanes (0 / 63) keep `old` (= own value); overridden by LDS fallback.
// ---------------------------------------------------------------------------
__device__ __forceinline__ float dpp_shr1(float v) {  // lane n <- lane n-1
  int r = __builtin_amdgcn_update_dpp(__float_as_int(v), __float_as_int(v),
                                      0x138, 0xF, 0xF, false);
  return __int_as_float(r);
}
__device__ __forceinline__ float dpp_shl1(float v) {  // lane n <- lane n+1
  int r = __builtin_amdgcn_update_dpp(__float_as_int(v), __float_as_int(v),
                                      0x130, 0xF, 0xF, false);
  return __int_as_float(r);
}

#define H2F(h) __half2float(h)

// ---------------------------------------------------------------------------
// Kernel 2: T=6 fused steps, 32x32 tile, X region 44x44 double-buffered.
// Thread owns 4-px group (xi, xj0..+3); K packed fp16 (16 half2 + 4 fp32 K0);
// own 4 px ride in c1. Edges via DPP; launch_bounds(512,6): 3 blocks/CU.
// ---------------------------------------------------------------------------
__global__ __launch_bounds__(NT, 6) void cspn_fused(
    const float* __restrict__ xin, const __half* __restrict__ Kh,
    float* __restrict__ xout) {
  __shared__ __align__(16) float sBuf[64 + 2 * XE + 64];  // front/back guards
  float* sX = sBuf + 64;

  int bid = blockIdx.x;
  int wg = (bid & 7) * (NTILES / 8) + (bid >> 3);  // XCD-chunked swizzle
  int b  = wg / (NTH * NTW);
  int rr = wg % (NTH * NTW);
  int ti0 = (rr / NTW) * TT, tj0 = (rr % NTW) * TT;
  int tid = threadIdx.x;
  int lane = tid & 63;

  bool active = tid < NGT;
  int xi  = 1 + tid / NG;          // 1..42
  int xj0 = (tid % NG) * 4;        // 0,4,...,40

  const float* xb = xin + (size_t)b * HW;

  // ---- issue staging loads FIRST (latency overlaps K load+unpack) ----
  int li0 = tid / (XR / 2), gc0 = tid - li0 * (XR / 2);
  int p1 = tid + NT;
  int li1 = p1 / (XR / 2), gc1 = p1 - li1 * (XR / 2);
  bool st1 = p1 < NF2;
  float2 sv0 = make_float2(0.f, 0.f), sv1 = make_float2(0.f, 0.f);
  {
    int gi = ti0 + li0 - T, gj = tj0 + 2 * gc0 - T;
    if ((unsigned)gi < (unsigned)H && (unsigned)gj < (unsigned)W)
      sv0 = *reinterpret_cast<const float2*>(xb + gi * W + gj);
  }
  if (st1) {
    int gi = ti0 + li1 - T, gj = tj0 + 2 * gc1 - T;
    if ((unsigned)gi < (unsigned)H && (unsigned)gj < (unsigned)W)
      sv1 = *reinterpret_cast<const float2*>(xb + gi * W + gj);
  }

  // ---- one-time K fragment: 4 px x half8, kept PACKED (16 half2 regs) ----
  __half2 kh[4][4];                // [px][tap-pair]
  float4 k0;                       // fp32 center tap per px
  {
    int gi  = ti0 + xi - T;
    int gj0 = tj0 + xj0 - T;
    bool rowv = active && (unsigned)gi < (unsigned)H;
    const __half* Kb =
        Kh + ((size_t)b * HW + (size_t)(rowv ? gi : 0) * W) * 8;
    float k0v[4];
#pragma unroll
    for (int p = 0; p < 4; ++p) {
      int gj = gj0 + p;
      union { uint4 u; __half2 h[4]; } pk;
      pk.u = make_uint4(0u, 0u, 0u, 0u);
      if (rowv && (unsigned)gj < (unsigned)W)
        pk.u = *reinterpret_cast<const uint4*>(Kb + (size_t)gj * 8);
      float2 f01 = __half22float2(pk.h[0]);
      float2 f23 = __half22float2(pk.h[1]);
      float2 f45 = __half22float2(pk.h[2]);
      float2 f67 = __half22float2(pk.h[3]);
      k0v[p] = 1.0f - (f01.x + f01.y + f23.x + f23.y +
                       f45.x + f45.y + f67.x + f67.y);
      kh[p][0] = pk.h[0]; kh[p][1] = pk.h[1];
      kh[p][2] = pk.h[2]; kh[p][3] = pk.h[3];
    }
    k0 = make_float4(k0v[0], k0v[1], k0v[2], k0v[3]);
  }

  // ---- write staged values to LDS buf0; zero guards + buf1 border rows ----
  *reinterpret_cast<float2*>(sX + li0 * XR + 2 * gc0) = sv0;
  if (st1) *reinterpret_cast<float2*>(sX + li1 * XR + 2 * gc1) = sv1;
  if (tid < 64) {
    sBuf[tid] = 0.f;
    sBuf[64 + 2 * XE + tid] = 0.f;
  }
  if (tid < 2 * XR) {              // buf1 rows 0 and 43
    int r = (tid < XR) ? 0 : (XR - 1);
    int c = (tid < XR) ? tid : tid - XR;
    sX[XE + r * XR + c] = 0.f;
  }
  __syncthreads();

  // ---- T fused steps; own 4 px live in c1; edges via DPP ----
  int base = xi * XR + xj0;
  float4 c1;
  if (active) c1 = *reinterpret_cast<const float4*>(sX + base);
#pragma unroll
  for (int s = 0; s < T; ++s) {
    const float* Xc = sX + (s & 1) * XE;
    float* Xn = sX + (((s & 1) ^ 1)) * XE;
    if (active) {
      float4 c0 = *reinterpret_cast<const float4*>(Xc + base - XR);
      float4 c2 = *reinterpret_cast<const float4*>(Xc + base + XR);
      // edges from neighbor lanes (bit-identical to the old LDS reads,
      // including the g-wrap case: lane-1's c1.w IS Xc[base-1]).
      float l0 = dpp_shr1(c0.w), l1 = dpp_shr1(c1.w), l2 = dpp_shr1(c2.w);
      float r0 = dpp_shl1(c0.x), r1 = dpp_shl1(c1.x), r2 = dpp_shl1(c2.x);
      if (lane == 0) {             // cross-wave boundary: 1-lane LDS reads
        l0 = Xc[base - XR - 1];
        l1 = Xc[base - 1];
        l2 = Xc[base + XR - 1];
      }
      if (lane == 63) {
        r0 = Xc[base - XR + 4];
        r1 = Xc[base + 4];
        r2 = Xc[base + XR + 4];
      }
      float4 acc;
      acc.x = k0.x * c1.x
            + H2F(kh[0][0].x) * l1   + H2F(kh[0][0].y) * c1.y
            + H2F(kh[0][1].x) * c0.x + H2F(kh[0][1].y) * l0
            + H2F(kh[0][2].x) * c0.y + H2F(kh[0][2].y) * c2.x
            + H2F(kh[0][3].x) * l2   + H2F(kh[0][3].y) * c2.y;
      acc.y = k0.y * c1.y
            + H2F(kh[1][0].x) * c1.x + H2F(kh[1][0].y) * c1.z
            + H2F(kh[1][1].x) * c0.y + H2F(kh[1][1].y) * c0.x
            + H2F(kh[1][2].x) * c0.z + H2F(kh[1][2].y) * c2.y
            + H2F(kh[1][3].x) * c2.x + H2F(kh[1][3].y) * c2.z;
      acc.z = k0.z * c1.z
            + H2F(kh[2][0].x) * c1.y + H2F(kh[2][0].y) * c1.w
            + H2F(kh[2][1].x) * c0.z + H2F(kh[2][1].y) * c0.y
            + H2F(kh[2][2].x) * c0.w + H2F(kh[2][2].y) * c2.z
            + H2F(kh[2][3].x) * c2.y + H2F(kh[2][3].y) * c2.w;
      acc.w = k0.w * c1.w
            + H2F(kh[3][0].x) * c1.z + H2F(kh[3][0].y) * r1
            + H2F(kh[3][1].x) * c0.w + H2F(kh[3][1].y) * c0.z
            + H2F(kh[3][2].x) * r0   + H2F(kh[3][2].y) * c2.w
            + H2F(kh[3][3].x) * c2.z + H2F(kh[3][3].y) * r2;
      *reinterpret_cast<float4*>(Xn + base) = acc;
      c1 = acc;
    }
    __syncthreads();
  }

  // ---- write 32x32 tile (step-6 result is in buf0; T even) ----
  float* yb = xout + (size_t)b * HW;
  int i  = tid >> 4;               // 0..31
  int pj = (tid & 15) * 2;         // 0..30
  float2 v = *reinterpret_cast<const float2*>(sX + (i + T) * XR + (pj + T));
  *reinterpret_cast<float2*>(yb + (size_t)(ti0 + i) * W + (tj0 + pj)) = v;
}

extern "C" void kernel_launch(void* const* d_in, const int* in_sizes, int n_in,
                              void* d_out, int out_size, void* d_ws,
                              size_t ws_size, hipStream_t stream) {
  const float* x  = (const float*)d_in[0];
  const float* Wa = (const float*)d_in[1];
  const float* ba = (const float*)d_in[2];
  float* out = (float*)d_out;

  __half* Kh = (__half*)d_ws;                   // 8N halves = 33.5 MB
  float* xa = (float*)d_ws + 4 * (size_t)N;     // after 16N bytes
  cspn_gen_kernel<<<dim3(N / 256), dim3(256), 0, stream>>>(x, Wa, ba, Kh);

  const float* src = x;
  for (int l = 0; l < 24 / T; ++l) {   // 4 launches of 6 fused steps
    float* dst = (l & 1) ? out : xa;   // l=3 (odd) -> final lands in d_out
    cspn_fused<<<dim3(NTILES), dim3(NT), 0, stream>>>(src, Kh, dst);
    src = dst;
  }
}